// Round 7
// baseline (226.196 us; speedup 1.0000x reference)
//
#include <hip/hip_runtime.h>
#include <hip/hip_bf16.h>

#define CDIV(a,b) (((a)+(b)-1)/(b))

typedef __bf16 bf16x8 __attribute__((ext_vector_type(8)));
typedef float  f32x4  __attribute__((ext_vector_type(4)));

union Frag16 { uint4 u; bf16x8 f; unsigned short s[8]; };
union Pack8  { unsigned short s[4]; uint2 u; };

__device__ __forceinline__ unsigned short f2bf(float f) {   // fp32 -> bf16 RNE
    unsigned u = __float_as_uint(f);
    return (unsigned short)((u + 0x7fff + ((u >> 16) & 1)) >> 16);
}
__device__ __forceinline__ float bf2f(unsigned short s) {
    return __uint_as_float(((unsigned)s) << 16);
}

__device__ __forceinline__ int load_src(const int* e, int f, int E, int i) {
    return f ? e[i] : e[2 * i];
}
__device__ __forceinline__ int load_dst(const int* e, int f, int E, int i) {
    return f ? e[E + i] : e[2 * (E + i)];
}

// ---------------------------------------------------------------------------
// prep: blocks 0,1 swizzle W1/W2 -> hi/lo bf16 MFMA B-fragments; block 2
// zeroes flag then samples edge layout (int64 LE => odd words all zero);
// blocks >=3 zero counts_sh.
// Fragment order: chunk c=(ntile*4+ks)*64+lane, 8 bf16:
//   B[k = ks*32 + (lane>>4)*8 + j][n = ntile*16 + (lane&15)]
// ---------------------------------------------------------------------------
__global__ __launch_bounds__(256) void prep_kernel(const float* __restrict__ W1,
                                                   const float* __restrict__ W2,
                                                   unsigned short* __restrict__ Wf1h,
                                                   unsigned short* __restrict__ Wf1l,
                                                   unsigned short* __restrict__ Wf2h,
                                                   unsigned short* __restrict__ Wf2l,
                                                   const int* __restrict__ edges,
                                                   int* __restrict__ flag, int E,
                                                   int4* __restrict__ zero_base, int Z4) {
    int tid = threadIdx.x;
    if (blockIdx.x == 2) {
        if (tid == 0) *flag = 0;
        __syncthreads();
        int n = min(E, 4096);
        int found = 0;
        for (int j = tid; j < n; j += 256) found |= (edges[2 * j + 1] != 0);
        if (found) *flag = 1;   // benign race within block
        return;
    }
    if (blockIdx.x >= 3) {
        int idx = (blockIdx.x - 3) * 256 + tid;
        if (idx < Z4) zero_base[idx] = make_int4(0, 0, 0, 0);
        return;
    }
    const float* W = (blockIdx.x == 0) ? W1 : W2;
    unsigned short* Wfh = (blockIdx.x == 0) ? Wf1h : Wf2h;
    unsigned short* Wfl = (blockIdx.x == 0) ? Wf1l : Wf2l;
    #pragma unroll
    for (int it = 0; it < 8; ++it) {
        int c = it * 256 + tid;           // chunk in [0, 2048)
        int ntk = c >> 6;
        int lane = c & 63;
        int ks = ntk & 3;
        int ntile = ntk >> 2;
        int quad = lane >> 4, nlo = lane & 15;
        int n = ntile * 16 + nlo;
        Frag16 h, l;
        #pragma unroll
        for (int j = 0; j < 8; ++j) {
            float w = W[(ks * 32 + quad * 8 + j) * 128 + n];
            h.s[j] = f2bf(w);
            float rr = w - bf2f(h.s[j]);
            l.s[j] = f2bf(rr);
        }
        *(uint4*)(Wfh + (size_t)c * 8) = h.u;
        *(uint4*)(Wfl + (size_t)c * 8) = l.u;
    }
}

// ---------------------------------------------------------------------------
// Split-bf16 MFMA GEMM body (fp32 input): out16 = bf16( X @ W ), fp32-accurate
// via xh*wh + xh*wl + xl*wh.  64 rows/block, 4 waves.
// ---------------------------------------------------------------------------
__device__ __forceinline__ void gemm_body(const float* __restrict__ X,
                                          const unsigned short* __restrict__ Wfh,
                                          const unsigned short* __restrict__ Wfl,
                                          unsigned short* __restrict__ out16,
                                          int N, int blk,
                                          unsigned short (*Xh)[136],
                                          unsigned short (*Xl)[136]) {
    int tid = threadIdx.x;
    int row0 = blk * 64;
    #pragma unroll
    for (int it = 0; it < 8; ++it) {
        int f = it * 256 + tid;           // 2048 float4 chunks
        int r = f >> 5, c4 = f & 31;
        float4 v = make_float4(0.f, 0.f, 0.f, 0.f);
        int gr = row0 + r;
        if (gr < N) v = *(const float4*)(X + (size_t)gr * 128 + c4 * 4);
        float vv[4] = {v.x, v.y, v.z, v.w};
        Pack8 h, l;
        #pragma unroll
        for (int j = 0; j < 4; ++j) {
            h.s[j] = f2bf(vv[j]);
            float rr = vv[j] - bf2f(h.s[j]);
            l.s[j] = f2bf(rr);
        }
        *(uint2*)(&Xh[r][c4 * 4]) = h.u;
        *(uint2*)(&Xl[r][c4 * 4]) = l.u;
    }
    __syncthreads();

    int lane = tid & 63;
    int wv = tid >> 6;
    int quad = lane >> 4, nlo = lane & 15;
    f32x4 acc[8];
    #pragma unroll
    for (int t = 0; t < 8; ++t) acc[t] = (f32x4){0.f, 0.f, 0.f, 0.f};

    #pragma unroll
    for (int ks = 0; ks < 4; ++ks) {
        int kcol = ks * 32 + quad * 8;
        Frag16 xh, xl;
        xh.u = *(const uint4*)(&Xh[wv * 16 + nlo][kcol]);
        xl.u = *(const uint4*)(&Xl[wv * 16 + nlo][kcol]);
        #pragma unroll
        for (int t = 0; t < 8; ++t) {
            size_t cidx = ((size_t)(t * 4 + ks) * 64 + lane) * 8;
            Frag16 wh, wl;
            wh.u = *(const uint4*)(Wfh + cidx);
            wl.u = *(const uint4*)(Wfl + cidx);
            acc[t] = __builtin_amdgcn_mfma_f32_16x16x32_bf16(xh.f, wh.f, acc[t], 0, 0, 0);
            acc[t] = __builtin_amdgcn_mfma_f32_16x16x32_bf16(xh.f, wl.f, acc[t], 0, 0, 0);
            acc[t] = __builtin_amdgcn_mfma_f32_16x16x32_bf16(xl.f, wh.f, acc[t], 0, 0, 0);
        }
    }
    // C/D layout: col = lane&15, row = quad*4 + reg
    #pragma unroll
    for (int rg = 0; rg < 4; ++rg) {
        int gr = row0 + wv * 16 + quad * 4 + rg;
        if (gr < N) {
            #pragma unroll
            for (int t = 0; t < 8; ++t)
                out16[(size_t)gr * 128 + t * 16 + nlo] = f2bf(acc[t][rg]);
        }
    }
}

// ---------------------------------------------------------------------------
// FAT kernel: blocks [0,Ggemm) do layer-1 GEMM (x@W1 -> A16); the rest do the
// degree count sharded by SRC BUCKET (src>>13, <=8 buckets of <=8192 nodes).
// Bucket-sharding makes fill emit each node's edges in src-bucket-major
// order => agg's resident waves walk ~the same 2MB H window together (L2).
// ---------------------------------------------------------------------------
__global__ __launch_bounds__(256) void fat_kernel(const float* __restrict__ X,
                                                  const unsigned short* __restrict__ Wfh,
                                                  const unsigned short* __restrict__ Wfl,
                                                  unsigned short* __restrict__ out16,
                                                  int N, int Ggemm,
                                                  const int* __restrict__ edges,
                                                  const int* __restrict__ flag,
                                                  int* __restrict__ counts_sh,
                                                  int* __restrict__ rank, int E) {
    __shared__ unsigned short Xh[64][136];   // +8 pad: 2-way conflicts only
    __shared__ unsigned short Xl[64][136];
    if (blockIdx.x < (unsigned)Ggemm) {
        gemm_body(X, Wfh, Wfl, out16, N, blockIdx.x, Xh, Xl);
        return;
    }
    int e = (blockIdx.x - Ggemm) * 256 + threadIdx.x;
    if (e >= E) return;
    int f = *flag;
    int d = load_dst(edges, f, E, e);
    int s = load_src(edges, f, E, e);
    int b = s >> 13;                       // src bucket (N<=65536 -> b in [0,8))
    int r = atomicAdd(&counts_sh[b * N + d], 1);
    rank[e] = (r << 3) | b;
}

// ---------------------------------------------------------------------------
// Layer-2 GEMM, bf16 input: A-fragments loaded DIRECTLY from global (row-major
// bf16 == A-frag layout: lane l holds A[m=l&15][k=(l>>4)*8+j]).  No LDS.
// ---------------------------------------------------------------------------
__global__ __launch_bounds__(256) void gemm_h1_kernel(const unsigned short* __restrict__ H1,
                                                      const unsigned short* __restrict__ Wfh,
                                                      const unsigned short* __restrict__ Wfl,
                                                      unsigned short* __restrict__ out16,
                                                      int N) {
    int tid = threadIdx.x;
    int lane = tid & 63, wv = tid >> 6;
    int quad = lane >> 4, nlo = lane & 15;
    int row0 = blockIdx.x * 64 + wv * 16;
    int arow = min(row0 + nlo, N - 1);        // clamp; OOB rows never stored
    Frag16 xa[4];
    #pragma unroll
    for (int ks = 0; ks < 4; ++ks)
        xa[ks].u = *(const uint4*)(H1 + (size_t)arow * 128 + ks * 32 + quad * 8);

    f32x4 acc[8];
    #pragma unroll
    for (int t = 0; t < 8; ++t) acc[t] = (f32x4){0.f, 0.f, 0.f, 0.f};

    #pragma unroll
    for (int ks = 0; ks < 4; ++ks) {
        #pragma unroll
        for (int t = 0; t < 8; ++t) {
            size_t cidx = ((size_t)(t * 4 + ks) * 64 + lane) * 8;
            Frag16 wh, wl;
            wh.u = *(const uint4*)(Wfh + cidx);
            wl.u = *(const uint4*)(Wfl + cidx);
            acc[t] = __builtin_amdgcn_mfma_f32_16x16x32_bf16(xa[ks].f, wh.f, acc[t], 0, 0, 0);
            acc[t] = __builtin_amdgcn_mfma_f32_16x16x32_bf16(xa[ks].f, wl.f, acc[t], 0, 0, 0);
        }
    }
    #pragma unroll
    for (int rg = 0; rg < 4; ++rg) {
        int gr = row0 + quad * 4 + rg;
        if (gr < N) {
            #pragma unroll
            for (int t = 0; t < 8; ++t)
                out16[(size_t)gr * 128 + t * 16 + nlo] = f2bf(acc[t][rg]);
        }
    }
}

// ---------------------------------------------------------------------------
// merge_dis: bucket counts -> bucket base offsets (in place), degree ->
// counts, dis = rsqrt(deg+1); per-1024-node sums -> bsum.
// ---------------------------------------------------------------------------
__global__ __launch_bounds__(256) void merge_dis_kernel(int* __restrict__ counts_sh,
                                                        int* __restrict__ counts,
                                                        float* __restrict__ dis,
                                                        int* __restrict__ bsum, int N) {
    __shared__ int red[4];
    int tid = threadIdx.x;
    int bs = 0;
    #pragma unroll
    for (int j = 0; j < 4; ++j) {
        int d = blockIdx.x * 1024 + j * 256 + tid;
        if (d < N) {
            int run = 0;
            #pragma unroll
            for (int s = 0; s < 8; ++s) {
                int v = counts_sh[s * N + d];
                counts_sh[s * N + d] = run;
                run += v;
            }
            counts[d] = run;
            dis[d] = rsqrtf((float)(run + 1));
            bs += run;
        }
    }
    #pragma unroll
    for (int off = 32; off >= 1; off >>= 1) bs += __shfl_down(bs, off, 64);
    if ((tid & 63) == 0) red[tid >> 6] = bs;
    __syncthreads();
    if (tid == 0) bsum[blockIdx.x] = red[0] + red[1] + red[2] + red[3];
}

// ---------------------------------------------------------------------------
// scan3 (scan2 folded in): wave 0 redundantly scans bsum[0..NB) (NB<=64) to
// get this block's base, then 1024-node local scan -> row_ptr.
// ---------------------------------------------------------------------------
__global__ __launch_bounds__(256) void scan3_kernel(const int* __restrict__ counts,
                                                    const int* __restrict__ bsum,
                                                    int* __restrict__ row_ptr,
                                                    int N, int NB, int E) {
    __shared__ int wsum[4];
    __shared__ int bo;
    int tid = threadIdx.x;
    int lane = tid & 63, wv = tid >> 6;
    if (wv == 0) {
        int v = (lane < NB) ? bsum[lane] : 0;
        int x = v;
        #pragma unroll
        for (int off = 1; off < 64; off <<= 1) {
            int t = __shfl_up(x, off, 64);
            if (lane >= off) x += t;
        }
        if (lane == (int)blockIdx.x) bo = x - v;   // exclusive prefix (NB<=64)
    }
    if (tid == 0 && blockIdx.x == 0) row_ptr[N] = E;
    int base = blockIdx.x * 1024 + tid * 4;
    int c[4];
    #pragma unroll
    for (int j = 0; j < 4; ++j) c[j] = (base + j < N) ? counts[base + j] : 0;
    int tsum = c[0] + c[1] + c[2] + c[3];
    int x = tsum;
    #pragma unroll
    for (int off = 1; off < 64; off <<= 1) {
        int t = __shfl_up(x, off, 64);
        if (lane >= off) x += t;
    }
    int texcl = x - tsum;
    if (lane == 63) wsum[wv] = x;
    __syncthreads();
    int woff = 0;
    for (int w = 0; w < wv; ++w) woff += wsum[w];
    int off0 = bo + woff + texcl;
    int run = 0;
    #pragma unroll
    for (int j = 0; j < 4; ++j) {
        if (base + j < N) row_ptr[base + j] = off0 + run;
        run += c[j];
    }
}

// CSR fill (atomic-free): pos = row_ptr[d] + bucket_base + local_rank.
// Result: each node's segment is src-bucket-major => agg L2 locality.
__global__ void fill_kernel(const int* __restrict__ edges, const int* __restrict__ flag,
                            const int* __restrict__ row_ptr, const int* __restrict__ rank,
                            const int* __restrict__ counts_sh,
                            const float* __restrict__ dis, int2* __restrict__ edata,
                            int E, int N) {
    int e = blockIdx.x * blockDim.x + threadIdx.x;
    if (e >= E) return;
    int f = *flag;
    int s = load_src(edges, f, E, e);
    int d = load_dst(edges, f, E, e);
    int rk = rank[e];
    int b = rk & 7;
    int pos = row_ptr[d] + counts_sh[b * N + d] + (rk >> 3);
    edata[pos] = make_int2(s, __float_as_int(dis[s]));
}

// ---------------------------------------------------------------------------
// Aggregation: one wave per node, bf16x2 (4B)/lane gathers, fp32 accumulate,
// bias+relu epilogue.  Unroll x16 (16 gathers in flight; avg degree ~17).
// Invalid slots alias edata[e] (broadcast, weight 0) => no extra traffic.
// ---------------------------------------------------------------------------
template <bool BF16OUT>
__global__ __launch_bounds__(256) void agg_kernel(const unsigned short* __restrict__ H16,
                                                  const int* __restrict__ row_ptr,
                                                  const int2* __restrict__ edata,
                                                  const float* __restrict__ dis,
                                                  const float* __restrict__ bias,
                                                  void* __restrict__ outp, int N) {
    int wid = (blockIdx.x * blockDim.x + threadIdx.x) >> 6;
    int lane = threadIdx.x & 63;
    if (wid >= N) return;
    const ushort2* H2 = (const ushort2*)H16;
    float dd = dis[wid];
    ushort2 hv = H2[(size_t)wid * 64 + lane];
    float wself = dd * dd;
    float2 acc = make_float2(bf2f(hv.x) * wself, bf2f(hv.y) * wself);
    int e0 = __builtin_amdgcn_readfirstlane(row_ptr[wid]);
    int e1 = __builtin_amdgcn_readfirstlane(row_ptr[wid + 1]);
    for (int e = e0; e < e1; e += 16) {
        int rem = e1 - e;
        int   sj[16];
        float wj[16];
        #pragma unroll
        for (int j = 0; j < 16; ++j) {
            bool valid = j < rem;
            int2 ed = edata[valid ? e + j : e];
            sj[j] = ed.x;
            wj[j] = valid ? __int_as_float(ed.y) * dd : 0.f;
        }
        ushort2 aj[16];
        #pragma unroll
        for (int j = 0; j < 16; ++j)
            aj[j] = H2[(size_t)sj[j] * 64 + lane];
        #pragma unroll
        for (int j = 0; j < 16; ++j) {
            acc.x += bf2f(aj[j].x) * wj[j];
            acc.y += bf2f(aj[j].y) * wj[j];
        }
    }
    float2 b = ((const float2*)bias)[lane];
    float ox = fmaxf(acc.x + b.x, 0.f);
    float oy = fmaxf(acc.y + b.y, 0.f);
    if (BF16OUT) {
        ushort2 o = make_ushort2(f2bf(ox), f2bf(oy));
        ((ushort2*)outp)[(size_t)wid * 64 + lane] = o;
    } else {
        ((float2*)outp)[(size_t)wid * 64 + lane] = make_float2(ox, oy);
    }
}

extern "C" void kernel_launch(void* const* d_in, const int* in_sizes, int n_in,
                              void* d_out, int out_size, void* d_ws, size_t ws_size,
                              hipStream_t stream) {
    const float* x    = (const float*)d_in[0];
    const int*  edges = (const int*)d_in[1];
    const float* W1   = (const float*)d_in[2];
    const float* b1   = (const float*)d_in[3];
    const float* W2   = (const float*)d_in[4];
    const float* b2   = (const float*)d_in[5];
    float* out = (float*)d_out;

    const int F = 128;
    const int N = in_sizes[0] / F;
    const int E = in_sizes[1] / 2;
    const int NB = CDIV(N, 1024);          // scan blocks (<=64 for folded scan)
    const int Ggemm = CDIV(N, 64);
    const int Gcount = CDIV(E, 256);

    #define AL4(v) (((v) + 3) & ~3)        // keep segments 16B-aligned
    unsigned short* A16 = (unsigned short*)d_ws;            // N*128 bf16 (gemm1 out; reused for h1@W2)
    unsigned short* H1  = A16 + (size_t)AL4(N * F);         // N*128 bf16 (agg1 out)
    float* dis      = (float*)(H1 + (size_t)AL4(N * F));    // N
    int*  counts    = (int*)(dis + AL4(N));                 // N
    int*  counts_sh = counts + AL4(N);                      // 8N  } zeroed by prep
    int*  flag      = counts_sh + AL4(8 * N);               // 4   } zeroed by prep blk2
    int*  row_ptr   = flag + 4;                             // N+4
    int*  bsum      = row_ptr + AL4(N + 1);                 // 64
    int*  rank      = bsum + 64;                            // E
    int2* edata     = (int2*)(rank + AL4(E));               // E
    unsigned short* Wf1h = (unsigned short*)(edata + E);    // 16384 each
    unsigned short* Wf1l = Wf1h + 16384;
    unsigned short* Wf2h = Wf1l + 16384;
    unsigned short* Wf2l = Wf2h + 16384;

    const int Z4 = AL4(8 * N) / 4;         // int4s of counts_sh to zero
    const int Gprep = 3 + CDIV(Z4, 256);

    prep_kernel<<<Gprep, 256, 0, stream>>>(W1, W2, Wf1h, Wf1l, Wf2h, Wf2l,
                                           edges, flag, E, (int4*)counts_sh, Z4);
    fat_kernel<<<Ggemm + Gcount, 256, 0, stream>>>(x, Wf1h, Wf1l, A16, N, Ggemm,
                                                   edges, flag, counts_sh, rank, E);
    merge_dis_kernel<<<NB, 256, 0, stream>>>(counts_sh, counts, dis, bsum, N);
    scan3_kernel<<<NB, 256, 0, stream>>>(counts, bsum, row_ptr, N, NB, E);
    fill_kernel<<<Gcount, 256, 0, stream>>>(edges, flag, row_ptr, rank,
                                            counts_sh, dis, edata, E, N);

    agg_kernel<true><<<CDIV(N * 64, 256), 256, 0, stream>>>(A16, row_ptr, edata, dis, b1, H1, N);
    gemm_h1_kernel<<<CDIV(N, 64), 256, 0, stream>>>(H1, Wf2h, Wf2l, A16, N);
    agg_kernel<false><<<CDIV(N * 64, 256), 256, 0, stream>>>(A16, row_ptr, edata, dis, b2, out, N);
}